// Round 18
// baseline (365.566 us; speedup 1.0000x reference)
//
#include <hip/hip_runtime.h>
#include <math.h>

#define NPATH 8192
#define NT    2048
#define NCF   6                 // even/odd coeffs each (deg 5 in y; full deg 11)
#define CPAD  16                // padded v2f stride per path
#define LM    (-3.75f)          // lv-range center  (lv in [-7, -0.5])
#define LR    (3.25f)           // lv-range half-width
#define SFX   2.8853900817779268f   // 2*log2(e)
#define LFX   1.4426950408889634f   // log2(e)

typedef float v2f __attribute__((ext_vector_type(2)));
typedef float v4f __attribute__((ext_vector_type(4)));

// ws float layout
#define W2P_F   0        // v2f w2pairs[k*32+j] = {W2dr[j][k], W2df[j][k]}  (2048 floats)
#define W1VP_F  2048     // v2f w1v pairs [32]
#define W3P_F   2112     // v2f w3 pairs  [32]
#define B2P_F   2176     // v2f b2 pairs  [32]
#define CST_F   2240     // b3dr, b3df, dt
#define CTAB_B  16384    // byte offset: v2f ctab[path][CPAD] = {mE0..mE5, mO0..mO5}

// TM[i][k] = coefficient of y^k in T_i(y), i,k in [0,5] (row-major, 6x6)
__device__ const float TMAT[36] = {
  1,0,0,0,0,0,
  0,1,0,0,0,0,
  -1,0,2,0,0,0,
  0,-3,0,4,0,0,
  1,0,-8,0,8,0,
  0,5,0,-20,0,16
};

__device__ __forceinline__ v2f vsplat(float x) { return (v2f){x, x}; }
__device__ __forceinline__ v2f vfma(v2f a, v2f b, v2f c) { return __builtin_elementwise_fma(a, b, c); }

__device__ __forceinline__ float tanh1(float z) {   // tanh(z) via exp2
    float e = __builtin_amdgcn_exp2f(SFX * z);
    return fmaf(__builtin_amdgcn_rcpf(1.0f + e), -2.0f, 1.0f);
}
__device__ __forceinline__ float sig1(float z) {    // sigmoid(z)
    float e = __builtin_amdgcn_exp2f(-LFX * z);
    return __builtin_amdgcn_rcpf(1.0f + e);
}
__device__ __forceinline__ v2f tanh2(v2f z) {
    v2f r; r.x = tanh1(z.x); r.y = tanh1(z.y); return r;
}

__global__ void prep_kernel(const float* __restrict__ drw1,
                            const float* __restrict__ drw2, const float* __restrict__ drb2,
                            const float* __restrict__ drw3, const float* __restrict__ drb3,
                            const float* __restrict__ dfw1,
                            const float* __restrict__ dfw2, const float* __restrict__ dfb2,
                            const float* __restrict__ dfw3, const float* __restrict__ dfb3,
                            const float* __restrict__ dtp, float* __restrict__ ws)
{
    int tid = threadIdx.x;
    for (int idx = tid; idx < 1024; idx += 256) {
        int k = idx >> 5, j = idx & 31;
        ws[W2P_F + 2 * idx]     = drw2[j * 32 + k];   // W2[j][k] pairs, k-major
        ws[W2P_F + 2 * idx + 1] = dfw2[j * 32 + k];
    }
    if (tid < 32) {
        ws[W1VP_F + 2 * tid]     = drw1[tid * 16 + 15];
        ws[W1VP_F + 2 * tid + 1] = dfw1[tid * 16 + 15];
        ws[W3P_F + 2 * tid]      = drw3[tid];
        ws[W3P_F + 2 * tid + 1]  = dfw3[tid];
        ws[B2P_F + 2 * tid]      = drb2[tid];
        ws[B2P_F + 2 * tid + 1]  = dfb2[tid];
    }
    if (tid == 0) {
        ws[CST_F]     = drb3[0];
        ws[CST_F + 1] = dfb3[0];
        ws[CST_F + 2] = dtp[0];
    }
}

// One 64-lane wave per path. Lane j evaluates both nets at Cheb node
// x_j = cos((j+.5)pi/64); even/odd split via shfl_xor(63); 32-lane DCT
// butterflies give Cheb coeffs of E(y),O(y) (deg 5 each); per-lane
// Cheb->monomial conversion. Coeffs prescaled by 1/LR (x-space state).
// O_F gets +1 on its constant term so the scan update is a single fma:
// x' = (E_F + x*(O_F+1)) + dw*(E_G + x*O_G).
__global__ __launch_bounds__(64) void build_kernel(
    const float* __restrict__ sig,
    const float* __restrict__ drw1, const float* __restrict__ drb1,
    const float* __restrict__ dfw1, const float* __restrict__ dfb1,
    const float* __restrict__ wconst, v2f* __restrict__ ctab)
{
    const int p = blockIdx.x;
    const int j = threadIdx.x;
    __shared__ v2f spv[32];            // pre pairs {dr, df} per hidden unit
    {
        int u = j & 31, net = j >> 5;
        const float* w1 = net ? dfw1 : drw1;
        const float* b1 = net ? dfb1 : drb1;
        float acc = b1[u];
#pragma unroll
        for (int m = 0; m < 15; ++m) acc = fmaf(sig[p * 15 + m], w1[u * 16 + m], acc);
        ((float*)spv)[2 * u + net] = acc;
    }
    __syncthreads();

    const float th = ((float)j + 0.5f) * (float)(M_PI / 64.0);
    const float xj = __cosf(th);
    const float v  = (LM + LR * xj) + 4.0f;        // v = lv + 4 at this node

    const v2f* __restrict__ w2p  = (const v2f*)(wconst + W2P_F);
    const v2f* __restrict__ w1vp = (const v2f*)(wconst + W1VP_F);
    const v2f* __restrict__ w3p  = (const v2f*)(wconst + W3P_F);
    const v2f* __restrict__ b2p  = (const v2f*)(wconst + B2P_F);

    v2f z3 = (v2f){wconst[CST_F], wconst[CST_F + 1]};

#pragma unroll
    for (int c = 0; c < 2; ++c) {          // two chunks of 16 output units
        v2f acc[16];
#pragma unroll
        for (int q = 0; q < 16; ++q) acc[q] = b2p[c * 16 + q];

#pragma unroll 8
        for (int k = 0; k < 32; ++k) {     // h recomputed per chunk
            v2f pre = spv[k];
            v2f z   = vfma(vsplat(v), w1vp[k], pre);
            v2f h   = tanh2(z);
            const v2f* col = w2p + k * 32 + c * 16;   // uniform -> s_load
#pragma unroll
            for (int q = 0; q < 16; ++q) acc[q] = vfma(col[q], h, acc[q]);
        }
#pragma unroll
        for (int q = 0; q < 16; ++q) {
            v2f a2 = tanh2(acc[q]);
            z3 = vfma(w3p[c * 16 + q], a2, z3);
        }
    }

    float dt = wconst[CST_F + 2];
    v2f Fj;
    Fj.x = 3.0f * tanh1(z3.x) * dt * (1.0f / LR);  // F = drift*dt/LR  (x-space)
    Fj.y = (sig1(z3.y) + 0.1f) * (1.0f / LR);      // G = diffusion/LR (x-space)

    // even/odd split: E = (F(x)+F(-x))/2, O = (F(x)-F(-x))/(2x); partner
    // lane is j^63 (x -> -x).
    v2f Fp;
    Fp.x = __shfl_xor(Fj.x, 63);
    Fp.y = __shfl_xor(Fj.y, 63);
    v2f E = (Fj + Fp) * 0.5f;
    float rx = 0.5f * __builtin_amdgcn_rcpf(xj);
    v2f O = (Fj - Fp) * vsplat(rx);

    // y-nodes: jj = j (half0) / 63-j (half1); theta2 = (jj+.5)pi/32.
    int jj = (j < 32) ? j : 63 - j;
    float th2 = ((float)jj + 0.5f) * (float)(M_PI / 32.0);

    v2f de[NCF], dq[NCF];
#pragma unroll
    for (int k = 0; k < NCF; ++k) {
        float ck = __cosf((float)k * th2);
        v2f tE = E * vsplat(ck);
        v2f tO = O * vsplat(ck);
#pragma unroll
        for (int m = 1; m < 32; m <<= 1) {         // 32-lane butterflies (halves independent)
            tE.x += __shfl_xor(tE.x, m); tE.y += __shfl_xor(tE.y, m);
            tO.x += __shfl_xor(tO.x, m); tO.y += __shfl_xor(tO.y, m);
        }
        float s = (k == 0) ? (1.0f / 32.0f) : (2.0f / 32.0f);
        de[k] = tE * vsplat(s);
        dq[k] = tO * vsplat(s);
    }

    // Cheb -> monomial: lane kk computes m_kk = sum_i d_i * TM[i][kk].
    // Lanes 0..5 -> E coeffs, lanes 16..21 -> O coeffs.
    int kk = j & 15; if (kk > 5) kk = 5;
    v2f m = vsplat(0.0f);
#pragma unroll
    for (int i = 0; i < NCF; ++i) {
        float a = TMAT[i * 6 + kk];
        m = vfma((j < 16) ? de[i] : dq[i], vsplat(a), m);
    }
    if (j == 16) m.x += 1.0f;                      // fold "+x" into O_F constant term
    if (j < 6)                  ctab[(size_t)p * CPAD + j]            = m;
    else if (j >= 16 && j < 22) ctab[(size_t)p * CPAD + 6 + (j - 16)] = m;
}

// One lane per path, r16 step body UNCHANGED (best per-step instr count).
// Launch geometry changed: 512-thread blocks -> 8 waves per CU = 2 waves
// per SIMD, so co-resident waves fill each other's issue-cadence dead
// slots (r1 evidence: VALUBusy 99% at 2 waves/SIMD). Grid 16 blocks.
__global__ __launch_bounds__(512) __attribute__((amdgpu_waves_per_eu(2)))
void scan_kernel(
    const float* __restrict__ init_var,
    const float* __restrict__ dW,
    const float* __restrict__ ws,
    float* __restrict__ out)
{
    const int path = blockIdx.x * 512 + threadIdx.x;
    const v2f* __restrict__ ct = (const v2f*)((const char*)ws + CTAB_B) + (size_t)path * CPAD;

    v2f e0 = ct[0], e1 = ct[1], e2 = ct[2], e3 = ct[3], e4 = ct[4], e5 = ct[5];
    v2f q0 = ct[6], q1 = ct[7], q2 = ct[8], q3 = ct[9], q4 = ct[10], q5 = ct[11];
    asm volatile("" : "+v"(e0), "+v"(e1), "+v"(e2), "+v"(e3), "+v"(e4), "+v"(e5));
    asm volatile("" : "+v"(q0), "+v"(q1), "+v"(q2), "+v"(q3), "+v"(q4), "+v"(q5));

    float lv = logf(fminf(fmaxf(init_var[path], 0.005f), 0.2f));
    float x  = fmaf(lv, 1.0f / LR, -LM / LR);      // normalized state in [-1, 1]
    const float K1 = LFX * LR;                     // ev = exp2(K1*x + K0)
    const float K0 = LFX * LM;
    const float* __restrict__ dwrow = dW + (size_t)path * NT;
    float* __restrict__ outp = out + path;

    auto STEP = [&](float dw, int tt) {
        float y  = fmaf(x + x, x, -1.0f);
        float y2 = y * y;
        v2f yv = vsplat(y), y2v = vsplat(y2);
        v2f eA = vfma(yv, e1, e0);
        v2f eB = vfma(yv, e3, e2);
        v2f eC = vfma(yv, e5, e4);
        v2f qA = vfma(yv, q1, q0);
        v2f qB = vfma(yv, q3, q2);
        v2f qC = vfma(yv, q5, q4);
        float y4 = y2 * y2;
        v2f y4v = vsplat(y4);
        v2f bE = vfma(y2v, eB, eA);  bE = vfma(y4v, eC, bE);
        v2f bO = vfma(y2v, qB, qA);  bO = vfma(y4v, qC, bO);
        v2f val = vfma(vsplat(x), bO, bE);         // {x'+F (pre-dw), G}
        x = fmaf(val.y, dw, val.x);
        x = __builtin_amdgcn_fmed3f(x, -1.0f, 1.0f);
        float ev = __builtin_amdgcn_exp2f(fmaf(x, K1, K0));   // off-chain
        __builtin_nontemporal_store(ev, outp + (size_t)tt * NPATH);
    };

    // 16-step-deep dW register pipeline (plain cached loads; lines reused 4x)
    v4f buf0 = *(const v4f*)(dwrow + 0);
    v4f buf1 = *(const v4f*)(dwrow + 4);
    v4f buf2 = *(const v4f*)(dwrow + 8);
    v4f buf3 = *(const v4f*)(dwrow + 12);
    for (int t = 0; t < NT; t += 4) {
        v4f cur = buf0;
        buf0 = buf1; buf1 = buf2; buf2 = buf3;
        if (t + 16 < NT) buf3 = *(const v4f*)(dwrow + t + 16);
        STEP(cur.x, t);
        STEP(cur.y, t + 1);
        STEP(cur.z, t + 2);
        STEP(cur.w, t + 3);
    }
}

extern "C" void kernel_launch(void* const* d_in, const int* in_sizes, int n_in,
                              void* d_out, int out_size, void* d_ws, size_t ws_size,
                              hipStream_t stream) {
    const float* init_var = (const float*)d_in[0];
    const float* sig      = (const float*)d_in[1];
    const float* dW       = (const float*)d_in[2];
    const float* dtp      = (const float*)d_in[3];
    const float* drw1     = (const float*)d_in[4];
    const float* drb1     = (const float*)d_in[5];
    const float* drw2     = (const float*)d_in[6];
    const float* drb2     = (const float*)d_in[7];
    const float* drw3     = (const float*)d_in[8];
    const float* drb3     = (const float*)d_in[9];
    const float* dfw1     = (const float*)d_in[10];
    const float* dfb1     = (const float*)d_in[11];
    const float* dfw2     = (const float*)d_in[12];
    const float* dfb2     = (const float*)d_in[13];
    const float* dfw3     = (const float*)d_in[14];
    const float* dfb3     = (const float*)d_in[15];
    float* out = (float*)d_out;
    float* ws  = (float*)d_ws;

    hipLaunchKernelGGL(prep_kernel, dim3(1), dim3(256), 0, stream,
                       drw1, drw2, drb2, drw3, drb3,
                       dfw1, dfw2, dfb2, dfw3, dfb3, dtp, ws);
    hipLaunchKernelGGL(build_kernel, dim3(NPATH), dim3(64), 0, stream,
                       sig, drw1, drb1, dfw1, dfb1,
                       ws, (v2f*)((char*)ws + CTAB_B));
    hipLaunchKernelGGL(scan_kernel, dim3(NPATH / 512), dim3(512), 0, stream,
                       init_var, dW, ws, out);
}

// Round 19
// 359.257 us; speedup vs baseline: 1.0176x; 1.0176x over previous
//
#include <hip/hip_runtime.h>
#include <math.h>

#define NPATH 8192
#define NT    2048
#define NCF   6                 // even/odd coeffs each (deg 5 in y; full deg 11)
#define CPAD  16                // padded v2f stride per path
#define LM    (-3.75f)          // lv-range center  (lv in [-7, -0.5])
#define LR    (3.25f)           // lv-range half-width
#define SFX   2.8853900817779268f   // 2*log2(e)
#define LFX   1.4426950408889634f   // log2(e)

typedef float v2f __attribute__((ext_vector_type(2)));
typedef float v4f __attribute__((ext_vector_type(4)));

// ws float layout
#define W2P_F   0        // v2f w2pairs[k*32+j] = {W2dr[j][k], W2df[j][k]}  (2048 floats)
#define W1VP_F  2048     // v2f w1v pairs [32]
#define W3P_F   2112     // v2f w3 pairs  [32]
#define B2P_F   2176     // v2f b2 pairs  [32]
#define CST_F   2240     // b3dr, b3df, dt
#define CTAB_B  16384    // byte offset: v2f ctab[path][CPAD] = {mE0..mE5, mO0..mO5}

// TM[i][k] = coefficient of y^k in T_i(y), i,k in [0,5] (row-major, 6x6)
__device__ const float TMAT[36] = {
  1,0,0,0,0,0,
  0,1,0,0,0,0,
  -1,0,2,0,0,0,
  0,-3,0,4,0,0,
  1,0,-8,0,8,0,
  0,5,0,-20,0,16
};

__device__ __forceinline__ v2f vsplat(float x) { return (v2f){x, x}; }
__device__ __forceinline__ v2f vfma(v2f a, v2f b, v2f c) { return __builtin_elementwise_fma(a, b, c); }

__device__ __forceinline__ float tanh1(float z) {   // tanh(z) via exp2
    float e = __builtin_amdgcn_exp2f(SFX * z);
    return fmaf(__builtin_amdgcn_rcpf(1.0f + e), -2.0f, 1.0f);
}
__device__ __forceinline__ float sig1(float z) {    // sigmoid(z)
    float e = __builtin_amdgcn_exp2f(-LFX * z);
    return __builtin_amdgcn_rcpf(1.0f + e);
}
__device__ __forceinline__ v2f tanh2(v2f z) {
    v2f r; r.x = tanh1(z.x); r.y = tanh1(z.y); return r;
}

__global__ void prep_kernel(const float* __restrict__ drw1,
                            const float* __restrict__ drw2, const float* __restrict__ drb2,
                            const float* __restrict__ drw3, const float* __restrict__ drb3,
                            const float* __restrict__ dfw1,
                            const float* __restrict__ dfw2, const float* __restrict__ dfb2,
                            const float* __restrict__ dfw3, const float* __restrict__ dfb3,
                            const float* __restrict__ dtp, float* __restrict__ ws)
{
    int tid = threadIdx.x;
    for (int idx = tid; idx < 1024; idx += 256) {
        int k = idx >> 5, j = idx & 31;
        ws[W2P_F + 2 * idx]     = drw2[j * 32 + k];   // W2[j][k] pairs, k-major
        ws[W2P_F + 2 * idx + 1] = dfw2[j * 32 + k];
    }
    if (tid < 32) {
        ws[W1VP_F + 2 * tid]     = drw1[tid * 16 + 15];
        ws[W1VP_F + 2 * tid + 1] = dfw1[tid * 16 + 15];
        ws[W3P_F + 2 * tid]      = drw3[tid];
        ws[W3P_F + 2 * tid + 1]  = dfw3[tid];
        ws[B2P_F + 2 * tid]      = drb2[tid];
        ws[B2P_F + 2 * tid + 1]  = dfb2[tid];
    }
    if (tid == 0) {
        ws[CST_F]     = drb3[0];
        ws[CST_F + 1] = dfb3[0];
        ws[CST_F + 2] = dtp[0];
    }
}

// One 64-lane wave per path. Lane j evaluates both nets at Cheb node
// x_j = cos((j+.5)pi/64); even/odd split via shfl_xor(63); 32-lane DCT
// butterflies give Cheb coeffs of E(y),O(y) (deg 5 each); per-lane
// Cheb->monomial conversion. Coeffs prescaled by 1/LR (x-space state).
// O_F gets +1 on its constant term so the scan update is a single fma:
// x' = (E_F + x*(O_F+1)) + dw*(E_G + x*O_G).
__global__ __launch_bounds__(64) void build_kernel(
    const float* __restrict__ sig,
    const float* __restrict__ drw1, const float* __restrict__ drb1,
    const float* __restrict__ dfw1, const float* __restrict__ dfb1,
    const float* __restrict__ wconst, v2f* __restrict__ ctab)
{
    const int p = blockIdx.x;
    const int j = threadIdx.x;
    __shared__ v2f spv[32];            // pre pairs {dr, df} per hidden unit
    {
        int u = j & 31, net = j >> 5;
        const float* w1 = net ? dfw1 : drw1;
        const float* b1 = net ? dfb1 : drb1;
        float acc = b1[u];
#pragma unroll
        for (int m = 0; m < 15; ++m) acc = fmaf(sig[p * 15 + m], w1[u * 16 + m], acc);
        ((float*)spv)[2 * u + net] = acc;
    }
    __syncthreads();

    const float th = ((float)j + 0.5f) * (float)(M_PI / 64.0);
    const float xj = __cosf(th);
    const float v  = (LM + LR * xj) + 4.0f;        // v = lv + 4 at this node

    const v2f* __restrict__ w2p  = (const v2f*)(wconst + W2P_F);
    const v2f* __restrict__ w1vp = (const v2f*)(wconst + W1VP_F);
    const v2f* __restrict__ w3p  = (const v2f*)(wconst + W3P_F);
    const v2f* __restrict__ b2p  = (const v2f*)(wconst + B2P_F);

    v2f z3 = (v2f){wconst[CST_F], wconst[CST_F + 1]};

#pragma unroll
    for (int c = 0; c < 2; ++c) {          // two chunks of 16 output units
        v2f acc[16];
#pragma unroll
        for (int q = 0; q < 16; ++q) acc[q] = b2p[c * 16 + q];

#pragma unroll 8
        for (int k = 0; k < 32; ++k) {     // h recomputed per chunk
            v2f pre = spv[k];
            v2f z   = vfma(vsplat(v), w1vp[k], pre);
            v2f h   = tanh2(z);
            const v2f* col = w2p + k * 32 + c * 16;   // uniform -> s_load
#pragma unroll
            for (int q = 0; q < 16; ++q) acc[q] = vfma(col[q], h, acc[q]);
        }
#pragma unroll
        for (int q = 0; q < 16; ++q) {
            v2f a2 = tanh2(acc[q]);
            z3 = vfma(w3p[c * 16 + q], a2, z3);
        }
    }

    float dt = wconst[CST_F + 2];
    v2f Fj;
    Fj.x = 3.0f * tanh1(z3.x) * dt * (1.0f / LR);  // F = drift*dt/LR  (x-space)
    Fj.y = (sig1(z3.y) + 0.1f) * (1.0f / LR);      // G = diffusion/LR (x-space)

    // even/odd split: E = (F(x)+F(-x))/2, O = (F(x)-F(-x))/(2x); partner
    // lane is j^63 (x -> -x).
    v2f Fp;
    Fp.x = __shfl_xor(Fj.x, 63);
    Fp.y = __shfl_xor(Fj.y, 63);
    v2f E = (Fj + Fp) * 0.5f;
    float rx = 0.5f * __builtin_amdgcn_rcpf(xj);
    v2f O = (Fj - Fp) * vsplat(rx);

    // y-nodes: jj = j (half0) / 63-j (half1); theta2 = (jj+.5)pi/32.
    int jj = (j < 32) ? j : 63 - j;
    float th2 = ((float)jj + 0.5f) * (float)(M_PI / 32.0);

    v2f de[NCF], dq[NCF];
#pragma unroll
    for (int k = 0; k < NCF; ++k) {
        float ck = __cosf((float)k * th2);
        v2f tE = E * vsplat(ck);
        v2f tO = O * vsplat(ck);
#pragma unroll
        for (int m = 1; m < 32; m <<= 1) {         // 32-lane butterflies (halves independent)
            tE.x += __shfl_xor(tE.x, m); tE.y += __shfl_xor(tE.y, m);
            tO.x += __shfl_xor(tO.x, m); tO.y += __shfl_xor(tO.y, m);
        }
        float s = (k == 0) ? (1.0f / 32.0f) : (2.0f / 32.0f);
        de[k] = tE * vsplat(s);
        dq[k] = tO * vsplat(s);
    }

    // Cheb -> monomial: lane kk computes m_kk = sum_i d_i * TM[i][kk].
    // Lanes 0..5 -> E coeffs, lanes 16..21 -> O coeffs.
    int kk = j & 15; if (kk > 5) kk = 5;
    v2f m = vsplat(0.0f);
#pragma unroll
    for (int i = 0; i < NCF; ++i) {
        float a = TMAT[i * 6 + kk];
        m = vfma((j < 16) ? de[i] : dq[i], vsplat(a), m);
    }
    if (j == 16) m.x += 1.0f;                      // fold "+x" into O_F constant term
    if (j < 6)                  ctab[(size_t)p * CPAD + j]            = m;
    else if (j >= 16 && j < 22) ctab[(size_t)p * CPAD + 6 + (j - 16)] = m;
}

// One lane per path, r16 step body UNCHANGED. Geometry: 512-thread blocks,
// grid 16 -> 128 waves on 16 CUs = 2 waves/SIMD (co-resident waves fill
// each other's issue-cadence dead slots). r18's VGPR-32 collapse fixed:
// explicit __launch_bounds__(512, 2) (VGPR cap 256, 1 block/CU) and
// persistent demand trimmed to ~55 regs (dW pipeline 12-deep).
__global__ __launch_bounds__(512, 2)
void scan_kernel(
    const float* __restrict__ init_var,
    const float* __restrict__ dW,
    const float* __restrict__ ws,
    float* __restrict__ out)
{
    const int path = blockIdx.x * 512 + threadIdx.x;
    const v2f* __restrict__ ct = (const v2f*)((const char*)ws + CTAB_B) + (size_t)path * CPAD;

    v2f e0 = ct[0], e1 = ct[1], e2 = ct[2], e3 = ct[3], e4 = ct[4], e5 = ct[5];
    v2f q0 = ct[6], q1 = ct[7], q2 = ct[8], q3 = ct[9], q4 = ct[10], q5 = ct[11];
    asm volatile("" : "+v"(e0), "+v"(e1), "+v"(e2), "+v"(e3), "+v"(e4), "+v"(e5));
    asm volatile("" : "+v"(q0), "+v"(q1), "+v"(q2), "+v"(q3), "+v"(q4), "+v"(q5));

    float lv = logf(fminf(fmaxf(init_var[path], 0.005f), 0.2f));
    float x  = fmaf(lv, 1.0f / LR, -LM / LR);      // normalized state in [-1, 1]
    const float K1 = LFX * LR;                     // ev = exp2(K1*x + K0)
    const float K0 = LFX * LM;
    const float* __restrict__ dwrow = dW + (size_t)path * NT;
    float* __restrict__ outp = out + path;

    auto STEP = [&](float dw, int tt) {
        float y  = fmaf(x + x, x, -1.0f);
        float y2 = y * y;
        v2f yv = vsplat(y), y2v = vsplat(y2);
        v2f eA = vfma(yv, e1, e0);
        v2f eB = vfma(yv, e3, e2);
        v2f eC = vfma(yv, e5, e4);
        v2f qA = vfma(yv, q1, q0);
        v2f qB = vfma(yv, q3, q2);
        v2f qC = vfma(yv, q5, q4);
        float y4 = y2 * y2;
        v2f y4v = vsplat(y4);
        v2f bE = vfma(y2v, eB, eA);  bE = vfma(y4v, eC, bE);
        v2f bO = vfma(y2v, qB, qA);  bO = vfma(y4v, qC, bO);
        v2f val = vfma(vsplat(x), bO, bE);         // {x'+F (pre-dw), G}
        x = fmaf(val.y, dw, val.x);
        x = __builtin_amdgcn_fmed3f(x, -1.0f, 1.0f);
        float ev = __builtin_amdgcn_exp2f(fmaf(x, K1, K0));   // off-chain
        __builtin_nontemporal_store(ev, outp + (size_t)tt * NPATH);
    };

    // 12-step-deep dW register pipeline (3 x v4f in flight)
    v4f buf0 = *(const v4f*)(dwrow + 0);
    v4f buf1 = *(const v4f*)(dwrow + 4);
    v4f buf2 = *(const v4f*)(dwrow + 8);
    for (int t = 0; t < NT; t += 4) {
        v4f cur = buf0;
        buf0 = buf1; buf1 = buf2;
        if (t + 12 < NT) buf2 = *(const v4f*)(dwrow + t + 12);
        STEP(cur.x, t);
        STEP(cur.y, t + 1);
        STEP(cur.z, t + 2);
        STEP(cur.w, t + 3);
    }
}

extern "C" void kernel_launch(void* const* d_in, const int* in_sizes, int n_in,
                              void* d_out, int out_size, void* d_ws, size_t ws_size,
                              hipStream_t stream) {
    const float* init_var = (const float*)d_in[0];
    const float* sig      = (const float*)d_in[1];
    const float* dW       = (const float*)d_in[2];
    const float* dtp      = (const float*)d_in[3];
    const float* drw1     = (const float*)d_in[4];
    const float* drb1     = (const float*)d_in[5];
    const float* drw2     = (const float*)d_in[6];
    const float* drb2     = (const float*)d_in[7];
    const float* drw3     = (const float*)d_in[8];
    const float* drb3     = (const float*)d_in[9];
    const float* dfw1     = (const float*)d_in[10];
    const float* dfb1     = (const float*)d_in[11];
    const float* dfw2     = (const float*)d_in[12];
    const float* dfb2     = (const float*)d_in[13];
    const float* dfw3     = (const float*)d_in[14];
    const float* dfb3     = (const float*)d_in[15];
    float* out = (float*)d_out;
    float* ws  = (float*)d_ws;

    hipLaunchKernelGGL(prep_kernel, dim3(1), dim3(256), 0, stream,
                       drw1, drw2, drb2, drw3, drb3,
                       dfw1, dfw2, dfb2, dfw3, dfb3, dtp, ws);
    hipLaunchKernelGGL(build_kernel, dim3(NPATH), dim3(64), 0, stream,
                       sig, drw1, drb1, dfw1, dfb1,
                       ws, (v2f*)((char*)ws + CTAB_B));
    hipLaunchKernelGGL(scan_kernel, dim3(NPATH / 512), dim3(512), 0, stream,
                       init_var, dW, ws, out);
}

// Round 20
// 340.530 us; speedup vs baseline: 1.0735x; 1.0550x over previous
//
#include <hip/hip_runtime.h>
#include <math.h>

#define NPATH 8192
#define NT    2048
#define NCF   6                 // even/odd coeffs each (deg 5 in y; full deg 11)
#define CPAD  16                // padded v2f stride per path (128 B)
#define LM    (-3.75f)          // lv-range center  (lv in [-7, -0.5])
#define LR    (3.25f)           // lv-range half-width
#define SFX   2.8853900817779268f   // 2*log2(e)
#define LFX   1.4426950408889634f   // log2(e)

typedef float v2f __attribute__((ext_vector_type(2)));
typedef float v4f __attribute__((ext_vector_type(4)));

// ws float layout
#define W2P_F   0        // v2f w2pairs[k*32+j] = {W2dr[j][k], W2df[j][k]}  (2048 floats)
#define W1VP_F  2048     // v2f w1v pairs [32]
#define W3P_F   2112     // v2f w3 pairs  [32]
#define B2P_F   2176     // v2f b2 pairs  [32]
#define CST_F   2240     // b3dr, b3df, dt
#define CTAB_B  16384    // byte offset: v2f ctab[path][CPAD] = {mE0..mE5, mO0..mO5}

// TM[i][k] = coefficient of y^k in T_i(y), i,k in [0,5] (row-major, 6x6)
__device__ const float TMAT[36] = {
  1,0,0,0,0,0,
  0,1,0,0,0,0,
  -1,0,2,0,0,0,
  0,-3,0,4,0,0,
  1,0,-8,0,8,0,
  0,5,0,-20,0,16
};

__device__ __forceinline__ v2f vsplat(float x) { return (v2f){x, x}; }
__device__ __forceinline__ v2f vfma(v2f a, v2f b, v2f c) { return __builtin_elementwise_fma(a, b, c); }

__device__ __forceinline__ float tanh1(float z) {   // tanh(z) via exp2
    float e = __builtin_amdgcn_exp2f(SFX * z);
    return fmaf(__builtin_amdgcn_rcpf(1.0f + e), -2.0f, 1.0f);
}
__device__ __forceinline__ float sig1(float z) {    // sigmoid(z)
    float e = __builtin_amdgcn_exp2f(-LFX * z);
    return __builtin_amdgcn_rcpf(1.0f + e);
}
__device__ __forceinline__ v2f tanh2(v2f z) {
    v2f r; r.x = tanh1(z.x); r.y = tanh1(z.y); return r;
}

__global__ void prep_kernel(const float* __restrict__ drw1,
                            const float* __restrict__ drw2, const float* __restrict__ drb2,
                            const float* __restrict__ drw3, const float* __restrict__ drb3,
                            const float* __restrict__ dfw1,
                            const float* __restrict__ dfw2, const float* __restrict__ dfb2,
                            const float* __restrict__ dfw3, const float* __restrict__ dfb3,
                            const float* __restrict__ dtp, float* __restrict__ ws)
{
    int tid = threadIdx.x;
    for (int idx = tid; idx < 1024; idx += 256) {
        int k = idx >> 5, j = idx & 31;
        ws[W2P_F + 2 * idx]     = drw2[j * 32 + k];   // W2[j][k] pairs, k-major
        ws[W2P_F + 2 * idx + 1] = dfw2[j * 32 + k];
    }
    if (tid < 32) {
        ws[W1VP_F + 2 * tid]     = drw1[tid * 16 + 15];
        ws[W1VP_F + 2 * tid + 1] = dfw1[tid * 16 + 15];
        ws[W3P_F + 2 * tid]      = drw3[tid];
        ws[W3P_F + 2 * tid + 1]  = dfw3[tid];
        ws[B2P_F + 2 * tid]      = drb2[tid];
        ws[B2P_F + 2 * tid + 1]  = dfb2[tid];
    }
    if (tid == 0) {
        ws[CST_F]     = drb3[0];
        ws[CST_F + 1] = dfb3[0];
        ws[CST_F + 2] = dtp[0];
    }
}

// One 64-lane wave per path. Lane j evaluates both nets at Cheb node
// x_j = cos((j+.5)pi/64); even/odd split via shfl_xor(63); 32-lane DCT
// butterflies give Cheb coeffs of E(y),O(y) (deg 5 each); per-lane
// Cheb->monomial conversion. Coeffs prescaled by 1/LR (x-space state).
// O_F gets +1 on its constant term so the scan update is a single fma.
__global__ __launch_bounds__(64) void build_kernel(
    const float* __restrict__ sig,
    const float* __restrict__ drw1, const float* __restrict__ drb1,
    const float* __restrict__ dfw1, const float* __restrict__ dfb1,
    const float* __restrict__ wconst, v2f* __restrict__ ctab)
{
    const int p = blockIdx.x;
    const int j = threadIdx.x;
    __shared__ v2f spv[32];            // pre pairs {dr, df} per hidden unit
    {
        int u = j & 31, net = j >> 5;
        const float* w1 = net ? dfw1 : drw1;
        const float* b1 = net ? dfb1 : drb1;
        float acc = b1[u];
#pragma unroll
        for (int m = 0; m < 15; ++m) acc = fmaf(sig[p * 15 + m], w1[u * 16 + m], acc);
        ((float*)spv)[2 * u + net] = acc;
    }
    __syncthreads();

    const float th = ((float)j + 0.5f) * (float)(M_PI / 64.0);
    const float xj = __cosf(th);
    const float v  = (LM + LR * xj) + 4.0f;        // v = lv + 4 at this node

    const v2f* __restrict__ w2p  = (const v2f*)(wconst + W2P_F);
    const v2f* __restrict__ w1vp = (const v2f*)(wconst + W1VP_F);
    const v2f* __restrict__ w3p  = (const v2f*)(wconst + W3P_F);
    const v2f* __restrict__ b2p  = (const v2f*)(wconst + B2P_F);

    v2f z3 = (v2f){wconst[CST_F], wconst[CST_F + 1]};

#pragma unroll
    for (int c = 0; c < 2; ++c) {          // two chunks of 16 output units
        v2f acc[16];
#pragma unroll
        for (int q = 0; q < 16; ++q) acc[q] = b2p[c * 16 + q];

#pragma unroll 8
        for (int k = 0; k < 32; ++k) {     // h recomputed per chunk
            v2f pre = spv[k];
            v2f z   = vfma(vsplat(v), w1vp[k], pre);
            v2f h   = tanh2(z);
            const v2f* col = w2p + k * 32 + c * 16;   // uniform -> s_load
#pragma unroll
            for (int q = 0; q < 16; ++q) acc[q] = vfma(col[q], h, acc[q]);
        }
#pragma unroll
        for (int q = 0; q < 16; ++q) {
            v2f a2 = tanh2(acc[q]);
            z3 = vfma(w3p[c * 16 + q], a2, z3);
        }
    }

    float dt = wconst[CST_F + 2];
    v2f Fj;
    Fj.x = 3.0f * tanh1(z3.x) * dt * (1.0f / LR);  // F = drift*dt/LR  (x-space)
    Fj.y = (sig1(z3.y) + 0.1f) * (1.0f / LR);      // G = diffusion/LR (x-space)

    // even/odd split: E = (F(x)+F(-x))/2, O = (F(x)-F(-x))/(2x); partner j^63
    v2f Fp;
    Fp.x = __shfl_xor(Fj.x, 63);
    Fp.y = __shfl_xor(Fj.y, 63);
    v2f E = (Fj + Fp) * 0.5f;
    float rx = 0.5f * __builtin_amdgcn_rcpf(xj);
    v2f O = (Fj - Fp) * vsplat(rx);

    int jj = (j < 32) ? j : 63 - j;
    float th2 = ((float)jj + 0.5f) * (float)(M_PI / 32.0);

    v2f de[NCF], dq[NCF];
#pragma unroll
    for (int k = 0; k < NCF; ++k) {
        float ck = __cosf((float)k * th2);
        v2f tE = E * vsplat(ck);
        v2f tO = O * vsplat(ck);
#pragma unroll
        for (int m = 1; m < 32; m <<= 1) {         // 32-lane butterflies
            tE.x += __shfl_xor(tE.x, m); tE.y += __shfl_xor(tE.y, m);
            tO.x += __shfl_xor(tO.x, m); tO.y += __shfl_xor(tO.y, m);
        }
        float s = (k == 0) ? (1.0f / 32.0f) : (2.0f / 32.0f);
        de[k] = tE * vsplat(s);
        dq[k] = tO * vsplat(s);
    }

    int kk = j & 15; if (kk > 5) kk = 5;
    v2f m = vsplat(0.0f);
#pragma unroll
    for (int i = 0; i < NCF; ++i) {
        float a = TMAT[i * 6 + kk];
        m = vfma((j < 16) ? de[i] : dq[i], vsplat(a), m);
    }
    if (j == 16) m.x += 1.0f;                      // fold "+x" into O_F constant term
    if (j < 6)                  ctab[(size_t)p * CPAD + j]            = m;
    else if (j >= 16 && j < 22) ctab[(size_t)p * CPAD + 6 + (j - 16)] = m;
}

// r16 step body; 512-thread blocks (2 waves/SIMD co-residency test).
// Coefficients loaded via inline-asm global_load_dwordx2 ("=v" outputs):
// values produced by opaque asm CANNOT be rematerialized, so the r18/r19
// sink-loads-into-loop collapse is illegal; demand ~60 VGPR < cap, so no
// scratch spill either. The vmcnt(0) asm takes all 12 values as "+v"
// in-outs so no use can be scheduled before the wait completes.
__global__ __launch_bounds__(512, 2)
void scan_kernel(
    const float* __restrict__ init_var,
    const float* __restrict__ dW,
    const float* __restrict__ ws,
    float* __restrict__ out)
{
    const int path = blockIdx.x * 512 + threadIdx.x;
    const v2f* __restrict__ ct = (const v2f*)((const char*)ws + CTAB_B) + (size_t)path * CPAD;

    v2f e0, e1, e2, e3, e4, e5, q0, q1, q2, q3, q4, q5;
    asm volatile("global_load_dwordx2 %0, %1, off offset:0"  : "=v"(e0) : "v"(ct));
    asm volatile("global_load_dwordx2 %0, %1, off offset:8"  : "=v"(e1) : "v"(ct));
    asm volatile("global_load_dwordx2 %0, %1, off offset:16" : "=v"(e2) : "v"(ct));
    asm volatile("global_load_dwordx2 %0, %1, off offset:24" : "=v"(e3) : "v"(ct));
    asm volatile("global_load_dwordx2 %0, %1, off offset:32" : "=v"(e4) : "v"(ct));
    asm volatile("global_load_dwordx2 %0, %1, off offset:40" : "=v"(e5) : "v"(ct));
    asm volatile("global_load_dwordx2 %0, %1, off offset:48" : "=v"(q0) : "v"(ct));
    asm volatile("global_load_dwordx2 %0, %1, off offset:56" : "=v"(q1) : "v"(ct));
    asm volatile("global_load_dwordx2 %0, %1, off offset:64" : "=v"(q2) : "v"(ct));
    asm volatile("global_load_dwordx2 %0, %1, off offset:72" : "=v"(q3) : "v"(ct));
    asm volatile("global_load_dwordx2 %0, %1, off offset:80" : "=v"(q4) : "v"(ct));
    asm volatile("global_load_dwordx2 %0, %1, off offset:88" : "=v"(q5) : "v"(ct));
    asm volatile("s_waitcnt vmcnt(0)"
                 : "+v"(e0), "+v"(e1), "+v"(e2), "+v"(e3), "+v"(e4), "+v"(e5),
                   "+v"(q0), "+v"(q1), "+v"(q2), "+v"(q3), "+v"(q4), "+v"(q5));

    float lv = logf(fminf(fmaxf(init_var[path], 0.005f), 0.2f));
    float x  = fmaf(lv, 1.0f / LR, -LM / LR);      // normalized state in [-1, 1]
    const float K1 = LFX * LR;                     // ev = exp2(K1*x + K0)
    const float K0 = LFX * LM;
    const float* __restrict__ dwrow = dW + (size_t)path * NT;
    float* __restrict__ outp = out + path;

    auto STEP = [&](float dw, int tt) {
        float y  = fmaf(x + x, x, -1.0f);
        float y2 = y * y;
        v2f yv = vsplat(y), y2v = vsplat(y2);
        v2f eA = vfma(yv, e1, e0);
        v2f eB = vfma(yv, e3, e2);
        v2f eC = vfma(yv, e5, e4);
        v2f qA = vfma(yv, q1, q0);
        v2f qB = vfma(yv, q3, q2);
        v2f qC = vfma(yv, q5, q4);
        float y4 = y2 * y2;
        v2f y4v = vsplat(y4);
        v2f bE = vfma(y2v, eB, eA);  bE = vfma(y4v, eC, bE);
        v2f bO = vfma(y2v, qB, qA);  bO = vfma(y4v, qC, bO);
        v2f val = vfma(vsplat(x), bO, bE);         // {x'+F (pre-dw), G}
        x = fmaf(val.y, dw, val.x);
        x = __builtin_amdgcn_fmed3f(x, -1.0f, 1.0f);
        float ev = __builtin_amdgcn_exp2f(fmaf(x, K1, K0));   // off-chain
        __builtin_nontemporal_store(ev, outp + (size_t)tt * NPATH);
    };

    // 12-step-deep dW register pipeline (3 x v4f in flight)
    v4f buf0 = *(const v4f*)(dwrow + 0);
    v4f buf1 = *(const v4f*)(dwrow + 4);
    v4f buf2 = *(const v4f*)(dwrow + 8);
    for (int t = 0; t < NT; t += 4) {
        v4f cur = buf0;
        buf0 = buf1; buf1 = buf2;
        if (t + 12 < NT) buf2 = *(const v4f*)(dwrow + t + 12);
        STEP(cur.x, t);
        STEP(cur.y, t + 1);
        STEP(cur.z, t + 2);
        STEP(cur.w, t + 3);
    }
}

extern "C" void kernel_launch(void* const* d_in, const int* in_sizes, int n_in,
                              void* d_out, int out_size, void* d_ws, size_t ws_size,
                              hipStream_t stream) {
    const float* init_var = (const float*)d_in[0];
    const float* sig      = (const float*)d_in[1];
    const float* dW       = (const float*)d_in[2];
    const float* dtp      = (const float*)d_in[3];
    const float* drw1     = (const float*)d_in[4];
    const float* drb1     = (const float*)d_in[5];
    const float* drw2     = (const float*)d_in[6];
    const float* drb2     = (const float*)d_in[7];
    const float* drw3     = (const float*)d_in[8];
    const float* drb3     = (const float*)d_in[9];
    const float* dfw1     = (const float*)d_in[10];
    const float* dfb1     = (const float*)d_in[11];
    const float* dfw2     = (const float*)d_in[12];
    const float* dfb2     = (const float*)d_in[13];
    const float* dfw3     = (const float*)d_in[14];
    const float* dfb3     = (const float*)d_in[15];
    float* out = (float*)d_out;
    float* ws  = (float*)d_ws;

    hipLaunchKernelGGL(prep_kernel, dim3(1), dim3(256), 0, stream,
                       drw1, drw2, drb2, drw3, drb3,
                       dfw1, dfw2, dfb2, dfw3, dfb3, dtp, ws);
    hipLaunchKernelGGL(build_kernel, dim3(NPATH), dim3(64), 0, stream,
                       sig, drw1, drb1, dfw1, dfb1,
                       ws, (v2f*)((char*)ws + CTAB_B));
    hipLaunchKernelGGL(scan_kernel, dim3(NPATH / 512), dim3(512), 0, stream,
                       init_var, dW, ws, out);
}

// Round 21
// 169.399 us; speedup vs baseline: 2.1580x; 2.0102x over previous
//
#include <hip/hip_runtime.h>
#include <math.h>

#define NPATH 8192
#define NT    2048
#define NCF   6                 // even/odd coeffs each (deg 5 in y; full deg 11)
#define CPAD  16                // padded v2f stride per path
#define LM    (-3.75f)          // lv-range center  (lv in [-7, -0.5])
#define LR    (3.25f)           // lv-range half-width
#define SFX   2.8853900817779268f   // 2*log2(e)
#define LFX   1.4426950408889634f   // log2(e)

typedef float v2f __attribute__((ext_vector_type(2)));
typedef float v4f __attribute__((ext_vector_type(4)));

// ws float layout
#define W2P_F   0        // v2f w2pairs[k*32+j] = {W2dr[j][k], W2df[j][k]}  (2048 floats)
#define W1VP_F  2048     // v2f w1v pairs [32]
#define W3P_F   2112     // v2f w3 pairs  [32]
#define B2P_F   2176     // v2f b2 pairs  [32]
#define CST_F   2240     // b3dr, b3df, dt
#define CTAB_B  16384    // byte offset: v2f ctab[path][CPAD] = {mE0..mE5, mO0..mO5}

// TM[i][k] = coefficient of y^k in T_i(y), i,k in [0,5] (row-major, 6x6)
__device__ const float TMAT[36] = {
  1,0,0,0,0,0,
  0,1,0,0,0,0,
  -1,0,2,0,0,0,
  0,-3,0,4,0,0,
  1,0,-8,0,8,0,
  0,5,0,-20,0,16
};

__device__ __forceinline__ v2f vsplat(float x) { return (v2f){x, x}; }
__device__ __forceinline__ v2f vfma(v2f a, v2f b, v2f c) { return __builtin_elementwise_fma(a, b, c); }

__device__ __forceinline__ float tanh1(float z) {   // tanh(z) via exp2
    float e = __builtin_amdgcn_exp2f(SFX * z);
    return fmaf(__builtin_amdgcn_rcpf(1.0f + e), -2.0f, 1.0f);
}
__device__ __forceinline__ float sig1(float z) {    // sigmoid(z)
    float e = __builtin_amdgcn_exp2f(-LFX * z);
    return __builtin_amdgcn_rcpf(1.0f + e);
}
__device__ __forceinline__ v2f tanh2(v2f z) {
    v2f r; r.x = tanh1(z.x); r.y = tanh1(z.y); return r;
}

__global__ void prep_kernel(const float* __restrict__ drw1,
                            const float* __restrict__ drw2, const float* __restrict__ drb2,
                            const float* __restrict__ drw3, const float* __restrict__ drb3,
                            const float* __restrict__ dfw1,
                            const float* __restrict__ dfw2, const float* __restrict__ dfb2,
                            const float* __restrict__ dfw3, const float* __restrict__ dfb3,
                            const float* __restrict__ dtp, float* __restrict__ ws)
{
    int tid = threadIdx.x;
    for (int idx = tid; idx < 1024; idx += 256) {
        int k = idx >> 5, j = idx & 31;
        ws[W2P_F + 2 * idx]     = drw2[j * 32 + k];   // W2[j][k] pairs, k-major
        ws[W2P_F + 2 * idx + 1] = dfw2[j * 32 + k];
    }
    if (tid < 32) {
        ws[W1VP_F + 2 * tid]     = drw1[tid * 16 + 15];
        ws[W1VP_F + 2 * tid + 1] = dfw1[tid * 16 + 15];
        ws[W3P_F + 2 * tid]      = drw3[tid];
        ws[W3P_F + 2 * tid + 1]  = dfw3[tid];
        ws[B2P_F + 2 * tid]      = drb2[tid];
        ws[B2P_F + 2 * tid + 1]  = dfb2[tid];
    }
    if (tid == 0) {
        ws[CST_F]     = drb3[0];
        ws[CST_F + 1] = dfb3[0];
        ws[CST_F + 2] = dtp[0];
    }
}

// One 64-lane wave per path. Lane j evaluates both nets at Cheb node
// x_j = cos((j+.5)pi/64); even/odd split via shfl_xor(63); 32-lane DCT
// butterflies give Cheb coeffs of E(y),O(y) (deg 5 each); per-lane
// Cheb->monomial conversion. Coeffs prescaled by 1/LR (x-space state).
// O_F gets +1 on its constant term so the scan update is a single fma.
__global__ __launch_bounds__(64) void build_kernel(
    const float* __restrict__ sig,
    const float* __restrict__ drw1, const float* __restrict__ drb1,
    const float* __restrict__ dfw1, const float* __restrict__ dfb1,
    const float* __restrict__ wconst, v2f* __restrict__ ctab)
{
    const int p = blockIdx.x;
    const int j = threadIdx.x;
    __shared__ v2f spv[32];            // pre pairs {dr, df} per hidden unit
    {
        int u = j & 31, net = j >> 5;
        const float* w1 = net ? dfw1 : drw1;
        const float* b1 = net ? dfb1 : drb1;
        float acc = b1[u];
#pragma unroll
        for (int m = 0; m < 15; ++m) acc = fmaf(sig[p * 15 + m], w1[u * 16 + m], acc);
        ((float*)spv)[2 * u + net] = acc;
    }
    __syncthreads();

    const float th = ((float)j + 0.5f) * (float)(M_PI / 64.0);
    const float xj = __cosf(th);
    const float v  = (LM + LR * xj) + 4.0f;        // v = lv + 4 at this node

    const v2f* __restrict__ w2p  = (const v2f*)(wconst + W2P_F);
    const v2f* __restrict__ w1vp = (const v2f*)(wconst + W1VP_F);
    const v2f* __restrict__ w3p  = (const v2f*)(wconst + W3P_F);
    const v2f* __restrict__ b2p  = (const v2f*)(wconst + B2P_F);

    v2f z3 = (v2f){wconst[CST_F], wconst[CST_F + 1]};

#pragma unroll
    for (int c = 0; c < 2; ++c) {          // two chunks of 16 output units
        v2f acc[16];
#pragma unroll
        for (int q = 0; q < 16; ++q) acc[q] = b2p[c * 16 + q];

#pragma unroll 8
        for (int k = 0; k < 32; ++k) {     // h recomputed per chunk
            v2f pre = spv[k];
            v2f z   = vfma(vsplat(v), w1vp[k], pre);
            v2f h   = tanh2(z);
            const v2f* col = w2p + k * 32 + c * 16;   // uniform -> s_load
#pragma unroll
            for (int q = 0; q < 16; ++q) acc[q] = vfma(col[q], h, acc[q]);
        }
#pragma unroll
        for (int q = 0; q < 16; ++q) {
            v2f a2 = tanh2(acc[q]);
            z3 = vfma(w3p[c * 16 + q], a2, z3);
        }
    }

    float dt = wconst[CST_F + 2];
    v2f Fj;
    Fj.x = 3.0f * tanh1(z3.x) * dt * (1.0f / LR);  // F = drift*dt/LR  (x-space)
    Fj.y = (sig1(z3.y) + 0.1f) * (1.0f / LR);      // G = diffusion/LR (x-space)

    // even/odd split: E = (F(x)+F(-x))/2, O = (F(x)-F(-x))/(2x); partner j^63
    v2f Fp;
    Fp.x = __shfl_xor(Fj.x, 63);
    Fp.y = __shfl_xor(Fj.y, 63);
    v2f E = (Fj + Fp) * 0.5f;
    float rx = 0.5f * __builtin_amdgcn_rcpf(xj);
    v2f O = (Fj - Fp) * vsplat(rx);

    int jj = (j < 32) ? j : 63 - j;
    float th2 = ((float)jj + 0.5f) * (float)(M_PI / 32.0);

    v2f de[NCF], dq[NCF];
#pragma unroll
    for (int k = 0; k < NCF; ++k) {
        float ck = __cosf((float)k * th2);
        v2f tE = E * vsplat(ck);
        v2f tO = O * vsplat(ck);
#pragma unroll
        for (int m = 1; m < 32; m <<= 1) {         // 32-lane butterflies
            tE.x += __shfl_xor(tE.x, m); tE.y += __shfl_xor(tE.y, m);
            tO.x += __shfl_xor(tO.x, m); tO.y += __shfl_xor(tO.y, m);
        }
        float s = (k == 0) ? (1.0f / 32.0f) : (2.0f / 32.0f);
        de[k] = tE * vsplat(s);
        dq[k] = tO * vsplat(s);
    }

    int kk = j & 15; if (kk > 5) kk = 5;
    v2f m = vsplat(0.0f);
#pragma unroll
    for (int i = 0; i < NCF; ++i) {
        float a = TMAT[i * 6 + kk];
        m = vfma((j < 16) ? de[i] : dq[i], vsplat(a), m);
    }
    if (j == 16) m.x += 1.0f;                      // fold "+x" into O_F constant term
    if (j < 6)                  ctab[(size_t)p * CPAD + j]            = m;
    else if (j >= 16 && j < 22) ctab[(size_t)p * CPAD + 6 + (j - 16)] = m;
}

// One lane per path, r16 math UNCHANGED, r16 geometry UNCHANGED (64-thread
// blocks = 1 wave/SIMD dedicated; proven VGPR-resident at 88). Loop
// restructured: 16-step unrolled body with 4 v4f dW buffers consumed in
// rotation and reloaded in place -> zero v_mov buffer shuffling (was
// ~2 inst/step) and 4x less loop overhead.
__global__ __launch_bounds__(64) __attribute__((amdgpu_waves_per_eu(1, 2)))
void scan_kernel(
    const float* __restrict__ init_var,
    const float* __restrict__ dW,
    const float* __restrict__ ws,
    float* __restrict__ out)
{
    const int lane = threadIdx.x;
    const int path = blockIdx.x * 64 + lane;
    const v2f* __restrict__ ct = (const v2f*)((const char*)ws + CTAB_B) + (size_t)path * CPAD;

    v2f e0 = ct[0], e1 = ct[1], e2 = ct[2], e3 = ct[3], e4 = ct[4], e5 = ct[5];
    v2f q0 = ct[6], q1 = ct[7], q2 = ct[8], q3 = ct[9], q4 = ct[10], q5 = ct[11];
    asm volatile("" : "+v"(e0), "+v"(e1), "+v"(e2), "+v"(e3), "+v"(e4), "+v"(e5));
    asm volatile("" : "+v"(q0), "+v"(q1), "+v"(q2), "+v"(q3), "+v"(q4), "+v"(q5));

    float lv = logf(fminf(fmaxf(init_var[path], 0.005f), 0.2f));
    float x  = fmaf(lv, 1.0f / LR, -LM / LR);      // normalized state in [-1, 1]
    const float K1 = LFX * LR;                     // ev = exp2(K1*x + K0)
    const float K0 = LFX * LM;
    const float* __restrict__ dwrow = dW + (size_t)path * NT;
    float* __restrict__ outp = out + path;

    auto STEP = [&](float dw, int tt) {
        float y  = fmaf(x + x, x, -1.0f);
        float y2 = y * y;
        v2f yv = vsplat(y), y2v = vsplat(y2);
        v2f eA = vfma(yv, e1, e0);
        v2f eB = vfma(yv, e3, e2);
        v2f eC = vfma(yv, e5, e4);
        v2f qA = vfma(yv, q1, q0);
        v2f qB = vfma(yv, q3, q2);
        v2f qC = vfma(yv, q5, q4);
        float y4 = y2 * y2;
        v2f y4v = vsplat(y4);
        v2f bE = vfma(y2v, eB, eA);  bE = vfma(y4v, eC, bE);
        v2f bO = vfma(y2v, qB, qA);  bO = vfma(y4v, qC, bO);
        v2f val = vfma(vsplat(x), bO, bE);         // {x'+F (pre-dw), G}
        x = fmaf(val.y, dw, val.x);
        x = __builtin_amdgcn_fmed3f(x, -1.0f, 1.0f);
        float ev = __builtin_amdgcn_exp2f(fmaf(x, K1, K0));   // off-chain
        __builtin_nontemporal_store(ev, outp + (size_t)tt * NPATH);
    };

    // 16-step unrolled main loop; 4 buffers reloaded in place (no movs).
    // NT = 2048 = 128 iterations exactly; reload 12-16 steps ahead of use.
    v4f b0 = *(const v4f*)(dwrow + 0);
    v4f b1 = *(const v4f*)(dwrow + 4);
    v4f b2 = *(const v4f*)(dwrow + 8);
    v4f b3 = *(const v4f*)(dwrow + 12);
    for (int t = 0; t < NT; t += 16) {
        STEP(b0.x, t);      STEP(b0.y, t + 1);  STEP(b0.z, t + 2);  STEP(b0.w, t + 3);
        if (t + 16 < NT) b0 = *(const v4f*)(dwrow + t + 16);
        STEP(b1.x, t + 4);  STEP(b1.y, t + 5);  STEP(b1.z, t + 6);  STEP(b1.w, t + 7);
        if (t + 20 < NT) b1 = *(const v4f*)(dwrow + t + 20);
        STEP(b2.x, t + 8);  STEP(b2.y, t + 9);  STEP(b2.z, t + 10); STEP(b2.w, t + 11);
        if (t + 24 < NT) b2 = *(const v4f*)(dwrow + t + 24);
        STEP(b3.x, t + 12); STEP(b3.y, t + 13); STEP(b3.z, t + 14); STEP(b3.w, t + 15);
        if (t + 28 < NT) b3 = *(const v4f*)(dwrow + t + 28);
    }
}

extern "C" void kernel_launch(void* const* d_in, const int* in_sizes, int n_in,
                              void* d_out, int out_size, void* d_ws, size_t ws_size,
                              hipStream_t stream) {
    const float* init_var = (const float*)d_in[0];
    const float* sig      = (const float*)d_in[1];
    const float* dW       = (const float*)d_in[2];
    const float* dtp      = (const float*)d_in[3];
    const float* drw1     = (const float*)d_in[4];
    const float* drb1     = (const float*)d_in[5];
    const float* drw2     = (const float*)d_in[6];
    const float* drb2     = (const float*)d_in[7];
    const float* drw3     = (const float*)d_in[8];
    const float* drb3     = (const float*)d_in[9];
    const float* dfw1     = (const float*)d_in[10];
    const float* dfb1     = (const float*)d_in[11];
    const float* dfw2     = (const float*)d_in[12];
    const float* dfb2     = (const float*)d_in[13];
    const float* dfw3     = (const float*)d_in[14];
    const float* dfb3     = (const float*)d_in[15];
    float* out = (float*)d_out;
    float* ws  = (float*)d_ws;

    hipLaunchKernelGGL(prep_kernel, dim3(1), dim3(256), 0, stream,
                       drw1, drw2, drb2, drw3, drb3,
                       dfw1, dfw2, dfb2, dfw3, dfb3, dtp, ws);
    hipLaunchKernelGGL(build_kernel, dim3(NPATH), dim3(64), 0, stream,
                       sig, drw1, drb1, dfw1, dfb1,
                       ws, (v2f*)((char*)ws + CTAB_B));
    hipLaunchKernelGGL(scan_kernel, dim3(NPATH / 64), dim3(64), 0, stream,
                       init_var, dW, ws, out);
}

// Round 22
// 160.758 us; speedup vs baseline: 2.2740x; 1.0538x over previous
//
#include <hip/hip_runtime.h>
#include <math.h>

#define NPATH 8192
#define NT    2048
#define NCF   5                 // even/odd coeffs each (deg 4 in y; full deg 9)
#define CPAD  16                // padded v2f stride per path
#define LM    (-3.75f)          // lv-range center  (lv in [-7, -0.5])
#define LR    (3.25f)           // lv-range half-width
#define SFX   2.8853900817779268f   // 2*log2(e)
#define LFX   1.4426950408889634f   // log2(e)

typedef float v2f __attribute__((ext_vector_type(2)));
typedef float v4f __attribute__((ext_vector_type(4)));

// ws float layout
#define W2P_F   0        // v2f w2pairs[k*32+j] = {W2dr[j][k], W2df[j][k]}  (2048 floats)
#define W1VP_F  2048     // v2f w1v pairs [32]
#define W3P_F   2112     // v2f w3 pairs  [32]
#define B2P_F   2176     // v2f b2 pairs  [32]
#define CST_F   2240     // b3dr, b3df, dt
#define CTAB_B  16384    // byte offset: v2f ctab[path][CPAD] = {mE0..mE4, mO0..mO4}

// TM[i][k] = coefficient of y^k in T_i(y), i,k in [0,4] (row-major, 5x5)
__device__ const float TMAT[25] = {
  1,0,0,0,0,
  0,1,0,0,0,
  -1,0,2,0,0,
  0,-3,0,4,0,
  1,0,-8,0,8
};

__device__ __forceinline__ v2f vsplat(float x) { return (v2f){x, x}; }
__device__ __forceinline__ v2f vfma(v2f a, v2f b, v2f c) { return __builtin_elementwise_fma(a, b, c); }

__device__ __forceinline__ float tanh1(float z) {   // tanh(z) via exp2
    float e = __builtin_amdgcn_exp2f(SFX * z);
    return fmaf(__builtin_amdgcn_rcpf(1.0f + e), -2.0f, 1.0f);
}
__device__ __forceinline__ float sig1(float z) {    // sigmoid(z)
    float e = __builtin_amdgcn_exp2f(-LFX * z);
    return __builtin_amdgcn_rcpf(1.0f + e);
}
__device__ __forceinline__ v2f tanh2(v2f z) {
    v2f r; r.x = tanh1(z.x); r.y = tanh1(z.y); return r;
}

__global__ void prep_kernel(const float* __restrict__ drw1,
                            const float* __restrict__ drw2, const float* __restrict__ drb2,
                            const float* __restrict__ drw3, const float* __restrict__ drb3,
                            const float* __restrict__ dfw1,
                            const float* __restrict__ dfw2, const float* __restrict__ dfb2,
                            const float* __restrict__ dfw3, const float* __restrict__ dfb3,
                            const float* __restrict__ dtp, float* __restrict__ ws)
{
    int tid = threadIdx.x;
    for (int idx = tid; idx < 1024; idx += 256) {
        int k = idx >> 5, j = idx & 31;
        ws[W2P_F + 2 * idx]     = drw2[j * 32 + k];   // W2[j][k] pairs, k-major
        ws[W2P_F + 2 * idx + 1] = dfw2[j * 32 + k];
    }
    if (tid < 32) {
        ws[W1VP_F + 2 * tid]     = drw1[tid * 16 + 15];
        ws[W1VP_F + 2 * tid + 1] = dfw1[tid * 16 + 15];
        ws[W3P_F + 2 * tid]      = drw3[tid];
        ws[W3P_F + 2 * tid + 1]  = dfw3[tid];
        ws[B2P_F + 2 * tid]      = drb2[tid];
        ws[B2P_F + 2 * tid + 1]  = dfb2[tid];
    }
    if (tid == 0) {
        ws[CST_F]     = drb3[0];
        ws[CST_F + 1] = dfb3[0];
        ws[CST_F + 2] = dtp[0];
    }
}

// One 64-lane wave per path. Lane j evaluates both nets at Cheb node
// x_j = cos((j+.5)pi/64); even/odd split via shfl_xor(63); 32-lane DCT
// butterflies give Cheb coeffs of E(y),O(y) (deg 4 each); per-lane
// Cheb->monomial conversion. Coeffs prescaled by 1/LR (x-space state).
// O_F gets +1 on its constant term so the scan update is a single fma.
__global__ __launch_bounds__(64) void build_kernel(
    const float* __restrict__ sig,
    const float* __restrict__ drw1, const float* __restrict__ drb1,
    const float* __restrict__ dfw1, const float* __restrict__ dfb1,
    const float* __restrict__ wconst, v2f* __restrict__ ctab)
{
    const int p = blockIdx.x;
    const int j = threadIdx.x;
    __shared__ v2f spv[32];            // pre pairs {dr, df} per hidden unit
    {
        int u = j & 31, net = j >> 5;
        const float* w1 = net ? dfw1 : drw1;
        const float* b1 = net ? dfb1 : drb1;
        float acc = b1[u];
#pragma unroll
        for (int m = 0; m < 15; ++m) acc = fmaf(sig[p * 15 + m], w1[u * 16 + m], acc);
        ((float*)spv)[2 * u + net] = acc;
    }
    __syncthreads();

    const float th = ((float)j + 0.5f) * (float)(M_PI / 64.0);
    const float xj = __cosf(th);
    const float v  = (LM + LR * xj) + 4.0f;        // v = lv + 4 at this node

    const v2f* __restrict__ w2p  = (const v2f*)(wconst + W2P_F);
    const v2f* __restrict__ w1vp = (const v2f*)(wconst + W1VP_F);
    const v2f* __restrict__ w3p  = (const v2f*)(wconst + W3P_F);
    const v2f* __restrict__ b2p  = (const v2f*)(wconst + B2P_F);

    v2f z3 = (v2f){wconst[CST_F], wconst[CST_F + 1]};

#pragma unroll
    for (int c = 0; c < 2; ++c) {          // two chunks of 16 output units
        v2f acc[16];
#pragma unroll
        for (int q = 0; q < 16; ++q) acc[q] = b2p[c * 16 + q];

#pragma unroll 8
        for (int k = 0; k < 32; ++k) {     // h recomputed per chunk
            v2f pre = spv[k];
            v2f z   = vfma(vsplat(v), w1vp[k], pre);
            v2f h   = tanh2(z);
            const v2f* col = w2p + k * 32 + c * 16;   // uniform -> s_load
#pragma unroll
            for (int q = 0; q < 16; ++q) acc[q] = vfma(col[q], h, acc[q]);
        }
#pragma unroll
        for (int q = 0; q < 16; ++q) {
            v2f a2 = tanh2(acc[q]);
            z3 = vfma(w3p[c * 16 + q], a2, z3);
        }
    }

    float dt = wconst[CST_F + 2];
    v2f Fj;
    Fj.x = 3.0f * tanh1(z3.x) * dt * (1.0f / LR);  // F = drift*dt/LR  (x-space)
    Fj.y = (sig1(z3.y) + 0.1f) * (1.0f / LR);      // G = diffusion/LR (x-space)

    // even/odd split: E = (F(x)+F(-x))/2, O = (F(x)-F(-x))/(2x); partner j^63
    v2f Fp;
    Fp.x = __shfl_xor(Fj.x, 63);
    Fp.y = __shfl_xor(Fj.y, 63);
    v2f E = (Fj + Fp) * 0.5f;
    float rx = 0.5f * __builtin_amdgcn_rcpf(xj);
    v2f O = (Fj - Fp) * vsplat(rx);

    int jj = (j < 32) ? j : 63 - j;
    float th2 = ((float)jj + 0.5f) * (float)(M_PI / 32.0);

    v2f de[NCF], dq[NCF];
#pragma unroll
    for (int k = 0; k < NCF; ++k) {
        float ck = __cosf((float)k * th2);
        v2f tE = E * vsplat(ck);
        v2f tO = O * vsplat(ck);
#pragma unroll
        for (int m = 1; m < 32; m <<= 1) {         // 32-lane butterflies
            tE.x += __shfl_xor(tE.x, m); tE.y += __shfl_xor(tE.y, m);
            tO.x += __shfl_xor(tO.x, m); tO.y += __shfl_xor(tO.y, m);
        }
        float s = (k == 0) ? (1.0f / 32.0f) : (2.0f / 32.0f);
        de[k] = tE * vsplat(s);
        dq[k] = tO * vsplat(s);
    }

    int kk = j & 15; if (kk > 4) kk = 4;
    v2f m = vsplat(0.0f);
#pragma unroll
    for (int i = 0; i < NCF; ++i) {
        float a = TMAT[i * 5 + kk];
        m = vfma((j < 16) ? de[i] : dq[i], vsplat(a), m);
    }
    if (j == 16) m.x += 1.0f;                      // fold "+x" into O_F constant term
    if (j < 5)                  ctab[(size_t)p * CPAD + j]            = m;
    else if (j >= 16 && j < 21) ctab[(size_t)p * CPAD + 5 + (j - 16)] = m;
}

// One lane per path; r21 structure (16-step unrolled loop, in-place dW
// buffer reloads, 64-thread blocks = dedicated SIMD/wave, coeffs named +
// asm-pinned). Degree reduced E/O 5->4: 8 pk_fma + val per step.
__global__ __launch_bounds__(64) __attribute__((amdgpu_waves_per_eu(1, 2)))
void scan_kernel(
    const float* __restrict__ init_var,
    const float* __restrict__ dW,
    const float* __restrict__ ws,
    float* __restrict__ out)
{
    const int lane = threadIdx.x;
    const int path = blockIdx.x * 64 + lane;
    const v2f* __restrict__ ct = (const v2f*)((const char*)ws + CTAB_B) + (size_t)path * CPAD;

    v2f e0 = ct[0], e1 = ct[1], e2 = ct[2], e3 = ct[3], e4 = ct[4];
    v2f q0 = ct[5], q1 = ct[6], q2 = ct[7], q3 = ct[8], q4 = ct[9];
    asm volatile("" : "+v"(e0), "+v"(e1), "+v"(e2), "+v"(e3), "+v"(e4));
    asm volatile("" : "+v"(q0), "+v"(q1), "+v"(q2), "+v"(q3), "+v"(q4));

    float lv = logf(fminf(fmaxf(init_var[path], 0.005f), 0.2f));
    float x  = fmaf(lv, 1.0f / LR, -LM / LR);      // normalized state in [-1, 1]
    const float K1 = LFX * LR;                     // ev = exp2(K1*x + K0)
    const float K0 = LFX * LM;
    const float* __restrict__ dwrow = dW + (size_t)path * NT;
    float* __restrict__ outp = out + path;

    auto STEP = [&](float dw, int tt) {
        float y  = fmaf(x + x, x, -1.0f);
        float y2 = y * y;
        v2f yv = vsplat(y), y2v = vsplat(y2);
        v2f eA = vfma(yv, e1, e0);
        v2f eB = vfma(yv, e3, e2);
        v2f qA = vfma(yv, q1, q0);
        v2f qB = vfma(yv, q3, q2);
        float y4 = y2 * y2;
        v2f y4v = vsplat(y4);
        v2f bE = vfma(y2v, eB, eA);  bE = vfma(y4v, e4, bE);
        v2f bO = vfma(y2v, qB, qA);  bO = vfma(y4v, q4, bO);
        v2f val = vfma(vsplat(x), bO, bE);         // {x'+F (pre-dw), G}
        x = fmaf(val.y, dw, val.x);
        x = __builtin_amdgcn_fmed3f(x, -1.0f, 1.0f);
        float ev = __builtin_amdgcn_exp2f(fmaf(x, K1, K0));   // off-chain
        __builtin_nontemporal_store(ev, outp + (size_t)tt * NPATH);
    };

    // 16-step unrolled main loop; 4 buffers reloaded in place (no movs).
    v4f b0 = *(const v4f*)(dwrow + 0);
    v4f b1 = *(const v4f*)(dwrow + 4);
    v4f b2 = *(const v4f*)(dwrow + 8);
    v4f b3 = *(const v4f*)(dwrow + 12);
    for (int t = 0; t < NT; t += 16) {
        STEP(b0.x, t);      STEP(b0.y, t + 1);  STEP(b0.z, t + 2);  STEP(b0.w, t + 3);
        if (t + 16 < NT) b0 = *(const v4f*)(dwrow + t + 16);
        STEP(b1.x, t + 4);  STEP(b1.y, t + 5);  STEP(b1.z, t + 6);  STEP(b1.w, t + 7);
        if (t + 20 < NT) b1 = *(const v4f*)(dwrow + t + 20);
        STEP(b2.x, t + 8);  STEP(b2.y, t + 9);  STEP(b2.z, t + 10); STEP(b2.w, t + 11);
        if (t + 24 < NT) b2 = *(const v4f*)(dwrow + t + 24);
        STEP(b3.x, t + 12); STEP(b3.y, t + 13); STEP(b3.z, t + 14); STEP(b3.w, t + 15);
        if (t + 28 < NT) b3 = *(const v4f*)(dwrow + t + 28);
    }
}

extern "C" void kernel_launch(void* const* d_in, const int* in_sizes, int n_in,
                              void* d_out, int out_size, void* d_ws, size_t ws_size,
                              hipStream_t stream) {
    const float* init_var = (const float*)d_in[0];
    const float* sig      = (const float*)d_in[1];
    const float* dW       = (const float*)d_in[2];
    const float* dtp      = (const float*)d_in[3];
    const float* drw1     = (const float*)d_in[4];
    const float* drb1     = (const float*)d_in[5];
    const float* drw2     = (const float*)d_in[6];
    const float* drb2     = (const float*)d_in[7];
    const float* drw3     = (const float*)d_in[8];
    const float* drb3     = (const float*)d_in[9];
    const float* dfw1     = (const float*)d_in[10];
    const float* dfb1     = (const float*)d_in[11];
    const float* dfw2     = (const float*)d_in[12];
    const float* dfb2     = (const float*)d_in[13];
    const float* dfw3     = (const float*)d_in[14];
    const float* dfb3     = (const float*)d_in[15];
    float* out = (float*)d_out;
    float* ws  = (float*)d_ws;

    hipLaunchKernelGGL(prep_kernel, dim3(1), dim3(256), 0, stream,
                       drw1, drw2, drb2, drw3, drb3,
                       dfw1, dfw2, dfb2, dfw3, dfb3, dtp, ws);
    hipLaunchKernelGGL(build_kernel, dim3(NPATH), dim3(64), 0, stream,
                       sig, drw1, drb1, dfw1, dfb1,
                       ws, (v2f*)((char*)ws + CTAB_B));
    hipLaunchKernelGGL(scan_kernel, dim3(NPATH / 64), dim3(64), 0, stream,
                       init_var, dW, ws, out);
}